// Round 6
// baseline (1016.476 us; speedup 1.0000x reference)
//
#include <hip/hip_runtime.h>

typedef short s16x8 __attribute__((ext_vector_type(8)));
typedef short s16x4 __attribute__((ext_vector_type(4)));
typedef float f32x4 __attribute__((ext_vector_type(4)));
typedef unsigned int u32;
typedef unsigned short u16;

#define NT 512
#define DD 64
#define NTH 512

#define CHUNK 1024

// ---------- recurrent kernel LDS (5 h-chunks per parity) ----------
#define P2STRIDE (5*CHUNK)
#define PH0 0
#define PH1 CHUNK
#define PH2 (2*CHUNK)
#define PH3 (3*CHUNK)
#define PH4 (4*CHUNK)
#define FRTOT2 (2*P2STRIDE)   // 10240 u16 = 20 KB
#define NSTEP2 517            // 512 + 5 pipeline stages

// ---------- fallback (round-3) LDS ----------
#define PSTRIDE (7*CHUNK)
#define XIN0 0
#define H0C (2*CHUNK)
#define H1C (3*CHUNK)
#define H2C (4*CHUNK)
#define H3C (5*CHUNK)
#define H4C (6*CHUNK)
#define FRTOT (2*PSTRIDE)
#define NSTEP_FB 517

#define MFMA16(A,B,C) __builtin_amdgcn_mfma_f32_16x16x32_bf16(A,B,C,0,0,0)

__device__ __forceinline__ float sigf(float x){ return 1.0f/(1.0f+__expf(-x)); }
__device__ __forceinline__ float tanhf2(float x){ return 2.0f/(1.0f+__expf(-2.0f*x)) - 1.0f; }

__device__ __forceinline__ u16 f2bf(float f) {
  u32 u = __builtin_bit_cast(u32, f);
  return (u16)((u + 0x7fffu + ((u >> 16) & 1u)) >> 16);
}
__device__ __forceinline__ float bf2f(u16 h) {
  u32 u = ((u32)h) << 16;
  return __builtin_bit_cast(float, u);
}

// barrier WITHOUT the vmcnt(0) drain: LDS visibility only (global ops drain at use)
__device__ __forceinline__ void soft_barrier() {
  asm volatile("s_waitcnt lgkmcnt(0)" ::: "memory");
  __builtin_amdgcn_s_barrier();
  asm volatile("" ::: "memory");
}

__device__ __forceinline__ u32 cvtpk_bf16(float a, float b) {
  u32 r;
  asm("v_cvt_pk_bf16_f32 %0, %1, %2" : "=v"(r) : "v"(a), "v"(b));
  return r;
}

// xor-8 lane swizzle (within 16-col group): partner lane = lane ^ 8
__device__ __forceinline__ float swzf(float v) {
  return __builtin_bit_cast(float,
      __builtin_amdgcn_ds_swizzle(__builtin_bit_cast(int, v), 0x201F));
}

// A-fragment: lane holds A[row0 + (lane&15)][kbase + (lane>>4)*8 + e], zero-padded.
__device__ __forceinline__ void load_wfrag(const float* __restrict__ W, int row0, int nrow, int din,
                                           int kbase, int lane, s16x8& hi, s16x8& lo)
{
  const int m = lane & 15, kb = lane >> 4;
#pragma unroll
  for (int e = 0; e < 8; ++e) {
    int k = kbase + kb*8 + e;
    float v = (m < nrow && k < din) ? W[(size_t)(row0 + m)*din + k] : 0.0f;
    u16 h = f2bf(v);
    hi[e] = (short)h;
    lo[e] = (short)f2bf(v - bf2f(h));
  }
}

// B-fragment read: lane reads B[k=(lane>>4)*8+e][col=lane&15] (hi at +0, lo at +128)
__device__ __forceinline__ void read_b(const u16* base, int lane, s16x8& hi, s16x8& lo)
{
  const int off = ((lane >> 4) << 8) + ((lane & 15) << 3);
  hi = *(const s16x8*)(base + off);
  lo = *(const s16x8*)(base + off + 128);
}

// lane-split gate combine: lanes bb<8 handle j-pair {0,1}, lanes bb>=8 take {2,3}
// via xor-8 swizzle. Only (bb&7)<4 columns are real at BB=4. Halves trans VALU.
template<bool NI_OWN>
__device__ __forceinline__ void combine_split(
    f32x4 aR, f32x4 aZ, f32x4 aNi, f32x4 aNh,
    float (&hp)[2], u16* dstC, int jt16, int nrow, int lane)
{
  const int bb = lane & 15, q = lane >> 4;
  const bool hihalf = (bb & 8) != 0;
  float sR2 = swzf(aR[2]), sR3 = swzf(aR[3]);
  float sZ2 = swzf(aZ[2]), sZ3 = swzf(aZ[3]);
  float sH2 = swzf(aNh[2]), sH3 = swzf(aNh[3]);
  float r0 = hihalf ? sR2 : aR[0],  r1 = hihalf ? sR3 : aR[1];
  float z0 = hihalf ? sZ2 : aZ[0],  z1 = hihalf ? sZ3 : aZ[1];
  float nh0 = hihalf ? sH2 : aNh[0], nh1 = hihalf ? sH3 : aNh[1];
  float ni0, ni1;
  if (NI_OWN) {          // gi duplicated across lane and lane^8 -> own regs valid
    ni0 = hihalf ? aNi[2] : aNi[0];
    ni1 = hihalf ? aNi[3] : aNi[1];
  } else {
    float sN2 = swzf(aNi[2]), sN3 = swzf(aNi[3]);
    ni0 = hihalf ? sN2 : aNi[0];
    ni1 = hihalf ? sN3 : aNi[1];
  }
  float rr0 = sigf(r0), rr1 = sigf(r1);
  float zz0 = sigf(z0), zz1 = sigf(z1);
  float n0 = tanhf2(ni0 + rr0*nh0), n1 = tanhf2(ni1 + rr1*nh1);
  float h0 = (1.0f - zz0)*n0 + zz0*hp[0];
  float h1 = (1.0f - zz1)*n1 + zz1*hp[1];
  hp[0] = h0; hp[1] = h1;
  const int jj = q*4 + (hihalf ? 2 : 0);
  if ((bb & 7) < 4 && jj < nrow) {
    const int j = jt16 + jj;
    u32 ph = cvtpk_bf16(h0, h1);
    float f0 = h0 - __builtin_bit_cast(float, ph << 16);
    float f1 = h1 - __builtin_bit_cast(float, ph & 0xffff0000u);
    u32 pl = cvtpk_bf16(f0, f1);
    u16* dst = dstC + ((j >> 3) << 8) + ((bb & 3) << 3) + (j & 7);
    *(u32*)dst = ph;
    *(u32*)(dst + 128) = pl;
  }
}

struct WTile {
  s16x8 Axh[3], Axl[3], Ahh[3], Ahl[3];
  f32x4 cR, cZ, cNi, cNh;
};

__device__ __forceinline__ void load_tile(WTile& w,
    const float* __restrict__ Wih, const float* __restrict__ Whh,
    const float* __restrict__ bih, const float* __restrict__ bhh,
    int jbase, int DH, int DIN, int nrow, int lane)
{
#pragma unroll
  for (int g = 0; g < 3; ++g) {
    load_wfrag(Wih, g*DH + jbase, nrow, DIN, 0, lane, w.Axh[g], w.Axl[g]);
    load_wfrag(Whh, g*DH + jbase, nrow, DH, 0, lane, w.Ahh[g], w.Ahl[g]);
  }
  const int q = lane >> 4;
#pragma unroll
  for (int i = 0; i < 4; ++i) {
    int lr = q*4 + i, j = jbase + lr;
    bool jr = lr < nrow;
    w.cR[i]  = jr ? bih[j] + bhh[j] : 0.f;
    w.cZ[i]  = jr ? bih[DH+j] + bhh[DH+j] : 0.f;
    w.cNi[i] = jr ? bih[2*DH+j] : 0.f;
    w.cNh[i] = jr ? bhh[2*DH+j] : 0.f;
  }
}

__device__ __forceinline__ void do_mid_tile(const WTile& w,
    const u16* bx, const u16* bhc, u16* dstC,
    float (&hp)[2], int jt16, int nrow, int lane)
{
  s16x8 bh_, bl_;
  read_b(bx, lane, bh_, bl_);
  f32x4 aR  = MFMA16(w.Axh[0], bh_, w.cR);
  aR  = MFMA16(w.Axh[0], bl_, aR);  aR  = MFMA16(w.Axl[0], bh_, aR);
  f32x4 aZ  = MFMA16(w.Axh[1], bh_, w.cZ);
  aZ  = MFMA16(w.Axh[1], bl_, aZ);  aZ  = MFMA16(w.Axl[1], bh_, aZ);
  f32x4 aNi = MFMA16(w.Axh[2], bh_, w.cNi);
  aNi = MFMA16(w.Axh[2], bl_, aNi); aNi = MFMA16(w.Axl[2], bh_, aNi);
  read_b(bhc, lane, bh_, bl_);
  aR  = MFMA16(w.Ahh[0], bh_, aR);  aR  = MFMA16(w.Ahh[0], bl_, aR);  aR  = MFMA16(w.Ahl[0], bh_, aR);
  aZ  = MFMA16(w.Ahh[1], bh_, aZ);  aZ  = MFMA16(w.Ahh[1], bl_, aZ);  aZ  = MFMA16(w.Ahl[1], bh_, aZ);
  f32x4 aNh = MFMA16(w.Ahh[2], bh_, w.cNh);
  aNh = MFMA16(w.Ahh[2], bl_, aNh); aNh = MFMA16(w.Ahl[2], bh_, aNh);
  combine_split<false>(aR, aZ, aNi, aNh, hp, dstC, jt16, nrow, lane);
}

// =====================================================================
// Phase 1: gi0[b][t][96] = Wih0 @ x_imp(b,t) + bih0 (+bhh0 for r,z rows)
// =====================================================================
__global__ __launch_bounds__(256)
void gi0_gemm(const float* __restrict__ X, const float* __restrict__ M, const float* __restrict__ L,
              const float* __restrict__ wih0, const float* __restrict__ bih0,
              const float* __restrict__ bhh0,
              float* __restrict__ gi)
{
  __shared__ u32 xs[128*65];
  const int tid = threadIdx.x;
  const int wv = tid >> 6, lane = tid & 63;
  const int q = lane >> 4;
  const int b = blockIdx.x >> 2;
  const int t0 = (blockIdx.x & 3) * 128;
  const size_t base = ((size_t)b*NT + t0)*DD;

  for (int i = tid; i < 128*64; i += 256) {
    float x = X[base+i], m = M[base+i], l = L[base+i];
    float v = x*m + l*(1.0f - m);
    u16 h = f2bf(v);
    u16 lo2 = f2bf(v - bf2f(h));
    const int t = i >> 6, d = i & 63;
    xs[t*65 + d] = (u32)h | ((u32)lo2 << 16);
  }

  s16x8 Ah[6][2], Al[6][2];
  f32x4 cb[6];
#pragma unroll
  for (int tile = 0; tile < 6; ++tile) {
#pragma unroll
    for (int c = 0; c < 2; ++c)
      load_wfrag(wih0, tile*16, 16, 64, c*32, lane, Ah[tile][c], Al[tile][c]);
#pragma unroll
    for (int i = 0; i < 4; ++i) {
      int row = tile*16 + q*4 + i;
      float bv = bih0[row];
      if (tile < 4) bv += bhh0[row];
      cb[tile][i] = bv;
    }
  }
  __syncthreads();

#pragma unroll
  for (int g2 = 0; g2 < 2; ++g2) {
    const int tloc = g2*64 + wv*16 + (lane & 15);
    s16x8 Bh[2], Bl[2];
#pragma unroll
    for (int c = 0; c < 2; ++c) {
      const u32* p = &xs[tloc*65 + c*32 + q*8];
#pragma unroll
      for (int e = 0; e < 8; ++e) {
        u32 v = p[e];
        Bh[c][e] = (short)(v & 0xffffu);
        Bl[c][e] = (short)(v >> 16);
      }
    }
    float* gp = gi + ((size_t)b*NT + t0 + tloc)*96 + q*4;
#pragma unroll
    for (int tile = 0; tile < 6; ++tile) {
      f32x4 acc = cb[tile];
#pragma unroll
      for (int c = 0; c < 2; ++c) {
        acc = MFMA16(Ah[tile][c], Bh[c], acc);
        acc = MFMA16(Ah[tile][c], Bl[c], acc);
        acc = MFMA16(Al[tile][c], Bh[c], acc);
      }
      *(f32x4*)(gp + tile*16) = acc;
    }
  }
}

// =====================================================================
// Phase 2: recurrent kernel — 4 waves/block, BB=4, 2 blocks/CU
// =====================================================================
__device__ void wv_l0(const float* __restrict__ whh0, const float* __restrict__ bhh0,
                      const float* __restrict__ gi, u16* FR, int b0, int lane)
{
  s16x8 Ahh[2][3], Ahl[2][3];
#pragma unroll
  for (int jt = 0; jt < 2; ++jt)
#pragma unroll
    for (int g = 0; g < 3; ++g)
      load_wfrag(whh0, g*32 + jt*16, 16, 32, 0, lane, Ahh[jt][g], Ahl[jt][g]);
  const int q = lane >> 4;
  f32x4 cNh[2];
#pragma unroll
  for (int jt = 0; jt < 2; ++jt)
#pragma unroll
    for (int i = 0; i < 4; ++i) cNh[jt][i] = bhh0[64 + jt*16 + q*4 + i];
  float hp[2][2] = {{0.f,0.f},{0.f,0.f}};

  const float* gp = gi + (size_t)(b0 + (lane & 3)) * ((size_t)NT*96) + q*4;
  f32x4 g0[2][3], g1[2][3];
#pragma unroll
  for (int jt = 0; jt < 2; ++jt) {
    g0[jt][0] = *(const f32x4*)(gp + jt*16);
    g0[jt][1] = *(const f32x4*)(gp + 32 + jt*16);
    g0[jt][2] = *(const f32x4*)(gp + 64 + jt*16);
  }
  gp += 96;
#pragma unroll
  for (int jt = 0; jt < 2; ++jt) {
    g1[jt][0] = *(const f32x4*)(gp + jt*16);
    g1[jt][1] = *(const f32x4*)(gp + 32 + jt*16);
    g1[jt][2] = *(const f32x4*)(gp + 64 + jt*16);
  }
  gp += 96;

  for (int s = 0; s < NSTEP2; ++s) {
    const int par = s & 1, rp = par ^ 1;
    f32x4 g2[2][3];
#pragma unroll
    for (int jt = 0; jt < 2; ++jt)
#pragma unroll
      for (int g = 0; g < 3; ++g) g2[jt][g] = f32x4{0.f,0.f,0.f,0.f};
    if (s + 2 < NT) {
#pragma unroll
      for (int jt = 0; jt < 2; ++jt) {
        g2[jt][0] = *(const f32x4*)(gp + jt*16);
        g2[jt][1] = *(const f32x4*)(gp + 32 + jt*16);
        g2[jt][2] = *(const f32x4*)(gp + 64 + jt*16);
      }
      gp += 96;
    }
    if (s < NT) {
      s16x8 bh_, bl_;
      read_b(FR + rp*P2STRIDE + PH0, lane, bh_, bl_);
#pragma unroll
      for (int jt = 0; jt < 2; ++jt) {
        f32x4 aR  = MFMA16(Ahh[jt][0], bh_, g0[jt][0]);
        aR  = MFMA16(Ahh[jt][0], bl_, aR);  aR  = MFMA16(Ahl[jt][0], bh_, aR);
        f32x4 aZ  = MFMA16(Ahh[jt][1], bh_, g0[jt][1]);
        aZ  = MFMA16(Ahh[jt][1], bl_, aZ);  aZ  = MFMA16(Ahl[jt][1], bh_, aZ);
        f32x4 aNh = MFMA16(Ahh[jt][2], bh_, cNh[jt]);
        aNh = MFMA16(Ahh[jt][2], bl_, aNh); aNh = MFMA16(Ahl[jt][2], bh_, aNh);
        combine_split<true>(aR, aZ, g0[jt][2], aNh, hp[jt],
                            FR + par*P2STRIDE + PH0, jt*16, 16, lane);
      }
    }
#pragma unroll
    for (int jt = 0; jt < 2; ++jt)
#pragma unroll
      for (int g = 0; g < 3; ++g) { g0[jt][g] = g1[jt][g]; g1[jt][g] = g2[jt][g]; }
    soft_barrier();
  }
}

__device__ void wv_l1_l2(
    const float* __restrict__ wih1, const float* __restrict__ whh1,
    const float* __restrict__ bih1, const float* __restrict__ bhh1,
    const float* __restrict__ wih2, const float* __restrict__ whh2,
    const float* __restrict__ bih2, const float* __restrict__ bhh2,
    u16* FR, int lane)
{
  WTile t1, t2;
  load_tile(t1, wih1, whh1, bih1, bhh1, 0, 16, 32, 16, lane);
  load_tile(t2, wih2, whh2, bih2, bhh2, 0,  8, 16,  8, lane);
  float hp1[2] = {0.f,0.f}, hp2[2] = {0.f,0.f};
  for (int s = 0; s < NSTEP2; ++s) {
    const int par = s & 1, rp = par ^ 1;
    const u16* R = FR + rp*P2STRIDE;
    u16* W = FR + par*P2STRIDE;
    if (s >= 1 && s <= 512) do_mid_tile(t1, R+PH0, R+PH1, W+PH1, hp1, 0, 16, lane);
    if (s >= 2 && s <= 513) do_mid_tile(t2, R+PH1, R+PH2, W+PH2, hp2, 0,  8, lane);
    soft_barrier();
  }
}

__device__ void wv_l3_l4b(
    const float* __restrict__ wih3, const float* __restrict__ whh3,
    const float* __restrict__ bih3, const float* __restrict__ bhh3,
    const float* __restrict__ wih4, const float* __restrict__ whh4,
    const float* __restrict__ bih4, const float* __restrict__ bhh4,
    u16* FR, int lane)
{
  WTile t3, t4b;
  load_tile(t3,  wih3, whh3, bih3, bhh3,  0, 16,  8, 16, lane);
  load_tile(t4b, wih4, whh4, bih4, bhh4, 16, 32, 16, 16, lane);
  float hp3[2] = {0.f,0.f}, hp4[2] = {0.f,0.f};
  for (int s = 0; s < NSTEP2; ++s) {
    const int par = s & 1, rp = par ^ 1;
    const u16* R = FR + rp*P2STRIDE;
    u16* W = FR + par*P2STRIDE;
    if (s >= 3 && s <= 514) do_mid_tile(t3,  R+PH2, R+PH3, W+PH3, hp3,  0, 16, lane);
    if (s >= 4 && s <= 515) do_mid_tile(t4b, R+PH3, R+PH4, W+PH4, hp4, 16, 16, lane);
    soft_barrier();
  }
}

__device__ void wv_l4a_out(
    const float* __restrict__ wih4, const float* __restrict__ whh4,
    const float* __restrict__ bih4, const float* __restrict__ bhh4,
    const float* __restrict__ OW, const float* __restrict__ OBb,
    u16* FR, float* __restrict__ out, int b0, int lane)
{
  WTile t4a;
  load_tile(t4a, wih4, whh4, bih4, bhh4, 0, 32, 16, 16, lane);
  float hp4[2] = {0.f,0.f};
  s16x8 Oh[4], Ol[4];
  f32x4 cO[4];
  const int q = lane >> 4, bb = lane & 15;
#pragma unroll
  for (int t4 = 0; t4 < 4; ++t4) {
    load_wfrag(OW, t4*16, 16, 32, 0, lane, Oh[t4], Ol[t4]);
#pragma unroll
    for (int i = 0; i < 4; ++i) cO[t4][i] = OBb[t4*16 + q*4 + i];
  }
  float* ob = out + ((size_t)(b0 + (bb & 3))*NT)*DD + q*4;

  for (int s = 0; s < NSTEP2; ++s) {
    const int par = s & 1, rp = par ^ 1;
    const u16* R = FR + rp*P2STRIDE;
    u16* W = FR + par*P2STRIDE;
    if (s >= 4 && s <= 515) do_mid_tile(t4a, R+PH3, R+PH4, W+PH4, hp4, 0, 16, lane);
    if (s >= 5) {
      s16x8 bh_, bl_;
      read_b(R + PH4, lane, bh_, bl_);
      float* op = ob + (size_t)(s-5)*DD;
#pragma unroll
      for (int t4 = 0; t4 < 4; ++t4) {
        f32x4 a_ = cO[t4];
        a_ = MFMA16(Oh[t4], bh_, a_); a_ = MFMA16(Oh[t4], bl_, a_); a_ = MFMA16(Ol[t4], bh_, a_);
        if (bb < 4) *(f32x4*)(op + t4*16) = a_;
      }
    }
    soft_barrier();
  }
}

__global__ __launch_bounds__(256, 2)
void gru_rec4(const float* __restrict__ gi,
              const float* __restrict__ whh0, const float* __restrict__ bhh0,
              const float* __restrict__ wih1, const float* __restrict__ whh1, const float* __restrict__ bih1, const float* __restrict__ bhh1,
              const float* __restrict__ wih2, const float* __restrict__ whh2, const float* __restrict__ bih2, const float* __restrict__ bhh2,
              const float* __restrict__ wih3, const float* __restrict__ whh3, const float* __restrict__ bih3, const float* __restrict__ bhh3,
              const float* __restrict__ wih4, const float* __restrict__ whh4, const float* __restrict__ bih4, const float* __restrict__ bhh4,
              const float* __restrict__ out_w, const float* __restrict__ out_b,
              float* __restrict__ out)
{
  __shared__ __align__(16) u16 FRu[FRTOT2];
  const int tid = threadIdx.x;
  const int w = tid >> 6, lane = tid & 63;
  const int b0 = blockIdx.x * 4;

  for (int i = tid; i < FRTOT2; i += 256) FRu[i] = 0;
  __syncthreads();

  if (w == 0)
    wv_l0(whh0, bhh0, gi, FRu, b0, lane);
  else if (w == 1)
    wv_l1_l2(wih1,whh1,bih1,bhh1, wih2,whh2,bih2,bhh2, FRu, lane);
  else if (w == 2)
    wv_l4a_out(wih4,whh4,bih4,bhh4, out_w, out_b, FRu, out, b0, lane);
  else
    wv_l3_l4b(wih3,whh3,bih3,bhh3, wih4,whh4,bih4,bhh4, FRu, lane);
}

// =====================================================================
// Fallback: round-3 kernel (used only if ws_size is too small for gi0)
// =====================================================================
__device__ __forceinline__ void combine_write(
    f32x4 aR, f32x4 aZ, f32x4 aNi, f32x4 aNh,
    float (&hprev)[4], u16* hdst_base, int jbase, int nrow, int lane)
{
  const int bb = lane & 15, q = lane >> 4;
  float hv[4];
#pragma unroll
  for (int i = 0; i < 4; ++i) {
    float rr = sigf(aR[i]);
    float zz = sigf(aZ[i]);
    float nn = tanhf2(aNi[i] + rr*aNh[i]);
    hv[i] = (1.0f - zz)*nn + zz*hprev[i];
    hprev[i] = hv[i];
  }
  if (bb < 8 && q*4 < nrow) {
    const int j = jbase + q*4;
    const int kb = j >> 3, e = j & 7;
    s16x4 hh, ll;
#pragma unroll
    for (int i = 0; i < 4; ++i) {
      u16 h = f2bf(hv[i]);
      hh[i] = (short)h;
      ll[i] = (short)f2bf(hv[i] - bf2f(h));
    }
    u16* dst = hdst_base + kb*256 + bb*8 + e;
    *(s16x4*)dst = hh;
    *(s16x4*)(dst + 128) = ll;
  }
}

__device__ __forceinline__ void write_x(u16* FRu, int par, int w, int lane, float v)
{
  const int d = lane;
  const int chunk = d >> 5, kb = (d >> 3) & 3, e = d & 7;
  u16 h = f2bf(v);
  u16 l2 = f2bf(v - bf2f(h));
  u16* p = FRu + par*PSTRIDE + XIN0 + chunk*CHUNK + kb*256 + w*8 + e;
  p[0] = h; p[128] = l2;
}

template<int DIN, int DH, int NXC>
__device__ __forceinline__ void wave_gru_fb(
    const float* __restrict__ Wih, const float* __restrict__ Whh,
    const float* __restrict__ bih, const float* __restrict__ bhh,
    int jbase, int xc, int hc, int s0, int s1,
    u16* FRu, float* OST,
    const float* __restrict__ X, const float* __restrict__ Mm, const float* __restrict__ Ll,
    float* __restrict__ out, int b0, int w, int lane)
{
  const int nrow = (DH - jbase) < 16 ? (DH - jbase) : 16;
  s16x8 Axh[3][NXC], Axl[3][NXC], Ahh[3], Ahl[3];
#pragma unroll
  for (int g = 0; g < 3; ++g) {
#pragma unroll
    for (int c = 0; c < NXC; ++c)
      load_wfrag(Wih, g*DH + jbase, nrow, DIN, c*32, lane, Axh[g][c], Axl[g][c]);
    load_wfrag(Whh, g*DH + jbase, nrow, DH, 0, lane, Ahh[g], Ahl[g]);
  }
  f32x4 cR, cZ, cNi, cNh;
  {
    const int q = lane >> 4;
#pragma unroll
    for (int i = 0; i < 4; ++i) {
      int lr = q*4 + i;
      int j = jbase + lr;
      bool jr = lr < nrow;
      cR[i]  = jr ? bih[j] + bhh[j] : 0.f;
      cZ[i]  = jr ? bih[DH+j] + bhh[DH+j] : 0.f;
      cNi[i] = jr ? bih[2*DH+j] : 0.f;
      cNh[i] = jr ? bhh[2*DH+j] : 0.f;
    }
  }
  float hprev[4] = {0.f, 0.f, 0.f, 0.f};

  const size_t gbase = ((size_t)(b0 + w))*((size_t)NT*DD) + lane;
  float rx = X[gbase], rm = Mm[gbase], rl = Ll[gbase];
  write_x(FRu, 1, w, lane, rx*rm + rl*(1.0f - rm));
  rx = X[gbase + DD]; rm = Mm[gbase + DD]; rl = Ll[gbase + DD];
  __syncthreads();

  for (int s = 0; s < NSTEP_FB; ++s) {
    const int par = s & 1, rp = par ^ 1;
    float nx = 0.f, nm = 0.f, nl = 0.f;
    if (s <= 509) {
      size_t g = gbase + (size_t)(s+2)*DD;
      nx = X[g]; nm = Mm[g]; nl = Ll[g];
    }
    f32x4 aR = cR, aZ = cZ, aNi = cNi, aNh = cNh;
    const bool run = (s >= s0) && (s <= s1);
    if (run) {
      const u16* RB = FRu + rp*PSTRIDE;
      s16x8 bh_, bl_;
#pragma unroll
      for (int c = 0; c < NXC; ++c) {
        read_b(RB + xc + c*CHUNK, lane, bh_, bl_);
        aR  = MFMA16(Axh[0][c], bh_, aR);  aR  = MFMA16(Axh[0][c], bl_, aR);  aR  = MFMA16(Axl[0][c], bh_, aR);
        aZ  = MFMA16(Axh[1][c], bh_, aZ);  aZ  = MFMA16(Axh[1][c], bl_, aZ);  aZ  = MFMA16(Axl[1][c], bh_, aZ);
        aNi = MFMA16(Axh[2][c], bh_, aNi); aNi = MFMA16(Axh[2][c], bl_, aNi); aNi = MFMA16(Axl[2][c], bh_, aNi);
      }
      read_b(RB + hc, lane, bh_, bl_);
      aR  = MFMA16(Ahh[0], bh_, aR);  aR  = MFMA16(Ahh[0], bl_, aR);  aR  = MFMA16(Ahl[0], bh_, aR);
      aZ  = MFMA16(Ahh[1], bh_, aZ);  aZ  = MFMA16(Ahh[1], bl_, aZ);  aZ  = MFMA16(Ahl[1], bh_, aZ);
      aNh = MFMA16(Ahh[2], bh_, aNh); aNh = MFMA16(Ahh[2], bl_, aNh); aNh = MFMA16(Ahl[2], bh_, aNh);
    }
    __syncthreads();

    if (run)
      combine_write(aR, aZ, aNi, aNh, hprev, FRu + par*PSTRIDE + hc, jbase, nrow, lane);
    if (s >= 5)
      out[((size_t)(b0 + w)*NT + (s-5))*DD + lane] = OST[w*65 + lane];
    if (s <= 510) write_x(FRu, par, w, lane, rx*rm + rl*(1.0f - rm));
    rx = nx; rm = nm; rl = nl;
    __syncthreads();
  }
}

__device__ __forceinline__ void wave_out_fb(
    const float* __restrict__ OW, const float* __restrict__ OBb,
    u16* FRu, float* OST,
    const float* __restrict__ X, const float* __restrict__ Mm, const float* __restrict__ Ll,
    float* __restrict__ out, int b0, int w, int lane)
{
  s16x8 Oh[4], Ol[4];
  f32x4 cO[4];
#pragma unroll
  for (int t4 = 0; t4 < 4; ++t4) {
    load_wfrag(OW, t4*16, 16, 32, 0, lane, Oh[t4], Ol[t4]);
#pragma unroll
    for (int i = 0; i < 4; ++i) cO[t4][i] = OBb[t4*16 + (lane>>4)*4 + i];
  }
  const size_t gbase = ((size_t)(b0 + w))*((size_t)NT*DD) + lane;
  float rx = X[gbase], rm = Mm[gbase], rl = Ll[gbase];
  write_x(FRu, 1, w, lane, rx*rm + rl*(1.0f - rm));
  rx = X[gbase + DD]; rm = Mm[gbase + DD]; rl = Ll[gbase + DD];
  __syncthreads();

  for (int s = 0; s < NSTEP_FB; ++s) {
    const int par = s & 1, rp = par ^ 1;
    float nx = 0.f, nm = 0.f, nl = 0.f;
    if (s <= 509) { size_t g = gbase + (size_t)(s+2)*DD; nx = X[g]; nm = Mm[g]; nl = Ll[g]; }
    if (s >= 5) {
      s16x8 bh_, bl_;
      read_b(FRu + rp*PSTRIDE + H4C, lane, bh_, bl_);
      const int bb = lane & 15, q = lane >> 4;
#pragma unroll
      for (int t4 = 0; t4 < 4; ++t4) {
        f32x4 a_ = cO[t4];
        a_ = MFMA16(Oh[t4], bh_, a_); a_ = MFMA16(Oh[t4], bl_, a_); a_ = MFMA16(Ol[t4], bh_, a_);
        if (bb < 8) {
#pragma unroll
          for (int i = 0; i < 4; ++i) OST[bb*65 + t4*16 + q*4 + i] = a_[i];
        }
      }
    }
    __syncthreads();
    if (s >= 5)
      out[((size_t)(b0 + w)*NT + (s-5))*DD + lane] = OST[w*65 + lane];
    if (s <= 510) write_x(FRu, par, w, lane, rx*rm + rl*(1.0f - rm));
    rx = nx; rm = nm; rl = nl;
    __syncthreads();
  }
}

__global__ __launch_bounds__(NTH, 1)
void gru_mfma(const float* __restrict__ X, const float* __restrict__ M, const float* __restrict__ L,
              const float* __restrict__ wih0, const float* __restrict__ whh0, const float* __restrict__ bih0, const float* __restrict__ bhh0,
              const float* __restrict__ wih1, const float* __restrict__ whh1, const float* __restrict__ bih1, const float* __restrict__ bhh1,
              const float* __restrict__ wih2, const float* __restrict__ whh2, const float* __restrict__ bih2, const float* __restrict__ bhh2,
              const float* __restrict__ wih3, const float* __restrict__ whh3, const float* __restrict__ bih3, const float* __restrict__ bhh3,
              const float* __restrict__ wih4, const float* __restrict__ whh4, const float* __restrict__ bih4, const float* __restrict__ bhh4,
              const float* __restrict__ out_w, const float* __restrict__ out_b,
              float* __restrict__ out)
{
  __shared__ __align__(16) u16 FRu[FRTOT];
  __shared__ float OST[8*65];
  const int tid = threadIdx.x;
  const int w = tid >> 6, lane = tid & 63;
  const int b0 = blockIdx.x * 8;

  for (int i = tid; i < FRTOT; i += NTH) FRu[i] = 0;
  for (int i = tid; i < 8*65; i += NTH) OST[i] = 0.f;
  __syncthreads();

  if (w == 0)
    wave_gru_fb<64,32,2>(wih0,whh0,bih0,bhh0,  0, XIN0, H0C, 0, 511, FRu, OST, X,M,L, out, b0, w, lane);
  else if (w == 1)
    wave_gru_fb<64,32,2>(wih0,whh0,bih0,bhh0, 16, XIN0, H0C, 0, 511, FRu, OST, X,M,L, out, b0, w, lane);
  else if (w == 2)
    wave_gru_fb<32,16,1>(wih1,whh1,bih1,bhh1,  0, H0C,  H1C, 1, 512, FRu, OST, X,M,L, out, b0, w, lane);
  else if (w == 4)
    wave_gru_fb<16, 8,1>(wih2,whh2,bih2,bhh2,  0, H1C,  H2C, 2, 513, FRu, OST, X,M,L, out, b0, w, lane);
  else if (w == 5)
    wave_gru_fb< 8,16,1>(wih3,whh3,bih3,bhh3,  0, H2C,  H3C, 3, 514, FRu, OST, X,M,L, out, b0, w, lane);
  else if (w == 3)
    wave_gru_fb<16,32,1>(wih4,whh4,bih4,bhh4,  0, H3C,  H4C, 4, 515, FRu, OST, X,M,L, out, b0, w, lane);
  else if (w == 6)
    wave_gru_fb<16,32,1>(wih4,whh4,bih4,bhh4, 16, H3C,  H4C, 4, 515, FRu, OST, X,M,L, out, b0, w, lane);
  else
    wave_out_fb(out_w, out_b, FRu, OST, X,M,L, out, b0, w, lane);
}

extern "C" void kernel_launch(void* const* d_in, const int* in_sizes, int n_in,
                              void* d_out, int out_size, void* d_ws, size_t ws_size,
                              hipStream_t stream)
{
  const float* X  = (const float*)d_in[0];
  const float* M  = (const float*)d_in[1];
  const float* L  = (const float*)d_in[2];
  const float* wp[20];
  for (int i = 0; i < 20; ++i) wp[i] = (const float*)d_in[3 + i];
  const float* ow = (const float*)d_in[23];
  const float* ob = (const float*)d_in[24];
  float* out = (float*)d_out;

  const size_t gi_bytes = (size_t)2048 * NT * 96 * sizeof(float);  // 402,653,184
  if (ws_size >= gi_bytes) {
    float* gi = (float*)d_ws;
    gi0_gemm<<<dim3(2048*4), dim3(256), 0, stream>>>(X, M, L, wp[0], wp[2], wp[3], gi);
    gru_rec4<<<dim3(512), dim3(256), 0, stream>>>(
        gi, wp[1], wp[3],
        wp[4], wp[5], wp[6], wp[7],
        wp[8], wp[9], wp[10], wp[11],
        wp[12], wp[13], wp[14], wp[15],
        wp[16], wp[17], wp[18], wp[19],
        ow, ob, out);
  } else {
    gru_mfma<<<dim3(256), dim3(NTH), 0, stream>>>(
        X, M, L,
        wp[0], wp[1], wp[2], wp[3],
        wp[4], wp[5], wp[6], wp[7],
        wp[8], wp[9], wp[10], wp[11],
        wp[12], wp[13], wp[14], wp[15],
        wp[16], wp[17], wp[18], wp[19],
        ow, ob, out);
  }
}